// Round 7
// baseline (1029.516 us; speedup 1.0000x reference)
//
#include <hip/hip_runtime.h>
#include <math.h>

#define T_TOK 32768
#define D_DIM 128
#define K_CODE 8192
#define BM 256              // tokens per block
#define BN 64               // codes per block
#define NSPLIT (K_CODE / BN)

typedef unsigned long long ull;

// ---------------- proj + fused cnorm ----------------
// One 64-thread block per code row. Thread l computes C[r][l] and C[r][64+l]
// with the SAME float4 fmaf sequence as R6's proj (bit-identical), then the
// SAME shfl_down chain as R6's cnorm (bit-identical cn).
__global__ __launch_bounds__(64) void proj_kernel(const float* __restrict__ E,
                                                  const float* __restrict__ W,
                                                  const float* __restrict__ b,
                                                  float* __restrict__ C,
                                                  float* __restrict__ cn) {
    int r = blockIdx.x;
    int l = threadIdx.x;          // 0..63
    const float4* E4 = (const float4*)(E + (size_t)r * D_DIM);
    const float4* WA = (const float4*)(W + (size_t)l * D_DIM);
    const float4* WB = (const float4*)(W + (size_t)(l + 64) * D_DIM);

    float4 aA = make_float4(0.f, 0.f, 0.f, 0.f);
    float4 aB = make_float4(0.f, 0.f, 0.f, 0.f);
#pragma unroll
    for (int dd = 0; dd < 32; ++dd) {
        float4 e = E4[dd];
        float4 wa = WA[dd], wb = WB[dd];
        aA.x = fmaf(e.x, wa.x, aA.x);
        aA.y = fmaf(e.y, wa.y, aA.y);
        aA.z = fmaf(e.z, wa.z, aA.z);
        aA.w = fmaf(e.w, wa.w, aA.w);
        aB.x = fmaf(e.x, wb.x, aB.x);
        aB.y = fmaf(e.y, wb.y, aB.y);
        aB.z = fmaf(e.z, wb.z, aB.z);
        aB.w = fmaf(e.w, wb.w, aB.w);
    }
    float vA = ((aA.x + aA.y) + (aA.z + aA.w)) + b[l];
    float vB = ((aB.x + aB.y) + (aB.z + aB.w)) + b[l + 64];
    C[r * D_DIM + l] = vA;
    C[r * D_DIM + 64 + l] = vB;

    float s = vA * vA + vB * vB;
#pragma unroll
    for (int off = 32; off > 0; off >>= 1) s += __shfl_down(s, off, 64);
    if (l == 0) cn[r] = s;
}

// ---------------- znorm (bit-identical) + fused inits ----------------
__global__ __launch_bounds__(64) void znorm_kernel(const float* __restrict__ Z,
                                                   float* __restrict__ zn,
                                                   ull* __restrict__ packed,
                                                   int* __restrict__ counts,
                                                   float* __restrict__ loss) {
    int t = blockIdx.x;
    int l = threadIdx.x;
    float a = Z[(size_t)t * D_DIM + l];
    float b2 = Z[(size_t)t * D_DIM + 64 + l];
    float s = a * a + b2 * b2;
#pragma unroll
    for (int off = 32; off > 0; off >>= 1) s += __shfl_down(s, off, 64);
    if (l == 0) {
        zn[t] = s;
        packed[t] = ~0ull;
        if (t < K_CODE) counts[t] = 0;
        if (t == 0) loss[0] = 0.f;
    }
}

// ---------------- transpose Z -> ZT[d][t] (ZT lives in d_out, dead until zq) --
__global__ __launch_bounds__(256) void transpose_kernel(const float* __restrict__ Z,
                                                        float* __restrict__ ZT) {
    __shared__ float tile[64][133];
    int tid = threadIdx.x;
    int tb = blockIdx.x * 64;
    const float4* Z4 = (const float4*)Z;
#pragma unroll
    for (int it = 0; it < 8; ++it) {
        int idx = it * 256 + tid;     // 0..2047
        int t = idx >> 5, f4 = idx & 31;
        float4 v = Z4[(size_t)(tb + t) * 32 + f4];
        tile[t][4 * f4 + 0] = v.x;
        tile[t][4 * f4 + 1] = v.y;
        tile[t][4 * f4 + 2] = v.z;
        tile[t][4 * f4 + 3] = v.w;
    }
    __syncthreads();
    float4* ZT4 = (float4*)ZT;
#pragma unroll
    for (int it = 0; it < 8; ++it) {
        int idx = it * 256 + tid;     // 0..2047
        int d = idx >> 4, t4 = idx & 15;
        float4 v = make_float4(tile[4 * t4 + 0][d], tile[4 * t4 + 1][d],
                               tile[4 * t4 + 2][d], tile[4 * t4 + 3][d]);
        ZT4[(size_t)d * (T_TOK / 4) + (tb >> 2) + t4] = v;
    }
}

// ---------------- GEMM-style argmin, barrier-free lean K-loop ----------------
// R6 lesson: VALUBusy 78% with ~35 extra VALU/k from bj[] movs + per-k addr
// recompute. Now: fmac fed straight from b128 results (no temp array), ZT
// pointer bumped once per 8-k chunk, flat LDS base + compile-time ds offsets
// (k*256B <= 32560 fits the 16-bit immediate).
__global__ __launch_bounds__(256, 4) void argmin_kernel(const float* __restrict__ ZT,
                                                        const float* __restrict__ C,
                                                        const float* __restrict__ cn,
                                                        const float* __restrict__ zn,
                                                        ull* __restrict__ packed) {
    __shared__ float Bs[D_DIM * BN];   // flat: Bs[k*64 + n], 32 KB

    int tid = threadIdx.x;
    int lane = tid & 63;
    int wid = __builtin_amdgcn_readfirstlane(tid >> 6);
    int nb = blockIdx.x * BN;         // x = codes: consecutive blocks share mb
    int mb = blockIdx.y * BM;
    int n0 = nb + wid * 16;

    // ---- stage whole-depth B tile once ----
    const float4* C4 = (const float4*)C;
#pragma unroll
    for (int it = 0; it < 8; ++it) {
        int idx = it * 256 + tid;     // 0..2047
        int n = idx & 63;
        int f4 = idx >> 6;            // 0..31
        float4 v = C4[(size_t)(nb + n) * 32 + f4];
        Bs[(4 * f4 + 0) * BN + n] = v.x;
        Bs[(4 * f4 + 1) * BN + n] = v.y;
        Bs[(4 * f4 + 2) * BN + n] = v.z;
        Bs[(4 * f4 + 3) * BN + n] = v.w;
    }
    __syncthreads();

    float acc[4][16];
#pragma unroll
    for (int i = 0; i < 4; ++i)
#pragma unroll
        for (int j = 0; j < 16; ++j) acc[i][j] = 0.f;

    const float4* zp = (const float4*)ZT + (mb >> 2) + lane;
    const float* bbase = &Bs[wid * 16];

#define FMA1(j, bval)                           \
    acc[0][j] = fmaf(av.x, bval, acc[0][j]);    \
    acc[1][j] = fmaf(av.y, bval, acc[1][j]);    \
    acc[2][j] = fmaf(av.z, bval, acc[2][j]);    \
    acc[3][j] = fmaf(av.w, bval, acc[3][j]);

    for (int kc = 0; kc < D_DIM / 8; ++kc) {
#pragma unroll
        for (int kk = 0; kk < 8; ++kk) {
            float4 av = zp[(size_t)kk * (T_TOK / 4)];
            const float* bp = bbase + kk * BN;
            float4 b0 = *(const float4*)(bp + 0);
            float4 b1 = *(const float4*)(bp + 4);
            float4 b2 = *(const float4*)(bp + 8);
            float4 b3 = *(const float4*)(bp + 12);
            FMA1(0, b0.x)  FMA1(1, b0.y)  FMA1(2, b0.z)  FMA1(3, b0.w)
            FMA1(4, b1.x)  FMA1(5, b1.y)  FMA1(6, b1.z)  FMA1(7, b1.w)
            FMA1(8, b2.x)  FMA1(9, b2.y)  FMA1(10, b2.z) FMA1(11, b2.w)
            FMA1(12, b3.x) FMA1(13, b3.y) FMA1(14, b3.z) FMA1(15, b3.w)
        }
        zp += 8 * (T_TOK / 4);
        bbase += 8 * BN;
    }
#undef FMA1

    // ---- epilogue: per-token argmin over this block's 64 codes ----
    int t0 = mb + 4 * lane;
    float4 znv = *(const float4*)&zn[t0];
    float zni[4] = {znv.x, znv.y, znv.z, znv.w};

    float bb[4];
    int   bi4[4];
#pragma unroll
    for (int i = 0; i < 4; ++i) {
        float best = 3.4e38f;
        int bidx = n0;
#pragma unroll
        for (int j = 0; j < 16; ++j) {
            // Match reference rounding: (|z|^2 + |c|^2) - 2*dot, elementwise fp32.
            float s = (zni[i] + cn[n0 + j]) - 2.f * acc[i][j];
            if (s < best) { best = s; bidx = n0 + j; }
        }
        bb[i] = best;
        bi4[i] = bidx;
    }

    __syncthreads();   // k-loop done in all waves before reusing Bs as scratch
    float* rb = &Bs[0];               // 4 x 256 floats
    int*   ri = (int*)&Bs[0] + 1024;
    *(float4*)&rb[wid * BM + 4 * lane] = make_float4(bb[0], bb[1], bb[2], bb[3]);
    *(int4*)&ri[wid * BM + 4 * lane] = make_int4(bi4[0], bi4[1], bi4[2], bi4[3]);
    __syncthreads();

    // one token per thread: reduce 4 waves (ascending wid = ascending code)
    {
        float best = rb[0 * BM + tid];
        int bidx = ri[0 * BM + tid];
#pragma unroll
        for (int w = 1; w < 4; ++w) {
            float v = rb[w * BM + tid];
            int i2 = ri[w * BM + tid];
            if (v < best) { best = v; bidx = i2; }
        }
        // d > 0 always, so f32 bits are monotone as uint; idx in low bits ->
        // ties resolve to smallest idx (first-min, matches argmin).
        ull pk = ((ull)__float_as_uint(best) << 32) | (unsigned)bidx;
        atomicMin(&packed[mb + tid], pk);
    }
}

// ---------------- zq (+ fused merge): unpack winner, gather, counts, loss ----
__global__ __launch_bounds__(256) void zq_kernel(const float* __restrict__ Z,
                                                 const float* __restrict__ C,
                                                 const ull* __restrict__ packed,
                                                 float* __restrict__ out,
                                                 int* __restrict__ counts,
                                                 float* __restrict__ loss) {
    int gid = blockIdx.x * 256 + threadIdx.x;   // over T*D/4 float4s
    int t = gid >> 5;                           // 32 float4 per token
    int d4 = gid & 31;
    int idx = (int)(packed[t] & 0xFFFFFFFFull);
    if (d4 == 0) atomicAdd(&counts[idx], 1);
    float4 cv = ((const float4*)C)[(size_t)idx * 32 + d4];
    float4 zv = ((const float4*)Z)[gid];
    float dx = cv.x - zv.x, dy = cv.y - zv.y, dz = cv.z - zv.z, dw = cv.w - zv.w;
    float4 o;
    o.x = zv.x + dx;    // z + (z_q - z): match reference elementwise rounding
    o.y = zv.y + dy;
    o.z = zv.z + dz;
    o.w = zv.w + dw;
    ((float4*)out)[gid] = o;

    float ls = dx * dx + dy * dy + dz * dz + dw * dw;
#pragma unroll
    for (int off = 32; off > 0; off >>= 1) ls += __shfl_down(ls, off, 64);
    __shared__ float red[4];
    int lane = threadIdx.x & 63, w = threadIdx.x >> 6;
    if (lane == 0) red[w] = ls;
    __syncthreads();
    if (threadIdx.x == 0) {
        atomicAdd(loss, (red[0] + red[1]) + (red[2] + red[3]));
    }
}

// ---------------- scalars: commit_loss, perplexity ----------------
__global__ __launch_bounds__(256) void scalars_kernel(const int* __restrict__ counts,
                                                      const float* __restrict__ loss,
                                                      float* __restrict__ out) {
    float s = 0.f;
    for (int i = threadIdx.x; i < K_CODE; i += 256) {
        float e = (float)counts[i] * (1.0f / (float)T_TOK);
        s += e * logf(e + 1e-8f);
    }
#pragma unroll
    for (int off = 32; off > 0; off >>= 1) s += __shfl_down(s, off, 64);
    __shared__ float red[4];
    int lane = threadIdx.x & 63, w = threadIdx.x >> 6;
    if (lane == 0) red[w] = s;
    __syncthreads();
    if (threadIdx.x == 0) {
        float ssum = (red[0] + red[1]) + (red[2] + red[3]);
        out[(size_t)T_TOK * D_DIM + 0] = 1.25f * loss[0] / (float)((size_t)T_TOK * D_DIM);
        out[(size_t)T_TOK * D_DIM + 1] = expf(-ssum);
    }
}

extern "C" void kernel_launch(void* const* d_in, const int* in_sizes, int n_in,
                              void* d_out, int out_size, void* d_ws, size_t ws_size,
                              hipStream_t stream) {
    const float* z   = (const float*)d_in[0];   // [8,4096,128]
    const float* emb = (const float*)d_in[1];   // [8192,128]
    const float* pw  = (const float*)d_in[2];   // [128,128]
    const float* pb  = (const float*)d_in[3];   // [128]
    float* out = (float*)d_out;

    // ZT (transposed z, 16 MB) lives in d_out: dead scratch until zq_kernel
    // overwrites d_out with the final z_q_st (scalars tail written after).
    float* ZT = out;

    char* ws = (char*)d_ws;
    // layout (bytes):
    //   C:      0        .. 4194304   (8192*128 f32)
    //   cn:     4194304  .. 4227072   (8192 f32)
    //   zn:     4227072  .. 4358144   (32768 f32)
    //   packed: 4358144  .. 4620288   (32768 u64)
    //   counts: 4620288  .. 4653056   (8192 i32)
    //   loss:   4653056  .. 4653060   (1 f32)
    float* C      = (float*)(ws + 0);
    float* cn     = (float*)(ws + 4194304);
    float* zn     = (float*)(ws + 4227072);
    ull*   packed = (ull*)  (ws + 4358144);
    int*   counts = (int*)  (ws + 4620288);
    float* loss   = (float*)(ws + 4653056);

    proj_kernel<<<K_CODE, 64, 0, stream>>>(emb, pw, pb, C, cn);
    transpose_kernel<<<T_TOK / 64, 256, 0, stream>>>(z, ZT);
    znorm_kernel<<<T_TOK, 64, 0, stream>>>(z, zn, packed, counts, loss);
    argmin_kernel<<<dim3(NSPLIT, T_TOK / BM), 256, 0, stream>>>(ZT, C, cn, zn, packed);
    zq_kernel<<<(T_TOK * D_DIM / 4) / 256, 256, 0, stream>>>(z, C, packed, out, counts, loss);
    scalars_kernel<<<1, 256, 0, stream>>>(counts, loss, out);
}

// Round 8
// 472.186 us; speedup vs baseline: 2.1803x; 2.1803x over previous
//
#include <hip/hip_runtime.h>
#include <math.h>

#define T_TOK 32768
#define D_DIM 128
#define K_CODE 8192
#define BM 256              // tokens per block (argmin)
#define BN 64               // codes per block (argmin)

typedef unsigned long long ull;
typedef _Float16 v8h __attribute__((ext_vector_type(8)));
typedef _Float16 v4h __attribute__((ext_vector_type(4)));
typedef float v16f __attribute__((ext_vector_type(16)));

#define SCALE 4096.0f        // 2^12: pushes f16 split residuals into normal range
#define DESCALE (1.0f / 4096.0f)
#define ACC_SCALE (-0x1p-23f)   // s = (zn+cn) - 2*dot, dot = acc*2^-24

// Cpack layout (bytes): [cb=code/64][ (s*2+mt)*8+kc ][lane64][j8 f16]
//   code r: cb=r>>6, mt=(r>>5)&1 ; element d: kc=d>>4, lane=((d>>3)&1)*32+(r&31), j=d&7
// Zpack layout (bytes): [tb=token/32][ s ][ kc ][lane64][j8 f16]
//   token t: tb=t>>5 ; lane=((d>>3)&1)*32+(t&31) ... identical frag rule.

// ---------------- proj: codebook row -> f16 split packs + cn ----------------
// Same fmaf/shfl sequences as R6/R7 (cn bit-identical). C fp32 is NOT stored;
// zq reconstructs c=(ch+cm)*2^-12 (exact: 11+11 mantissa bits span < 24).
__global__ __launch_bounds__(64) void proj_kernel(const float* __restrict__ E,
                                                  const float* __restrict__ W,
                                                  const float* __restrict__ b,
                                                  char* __restrict__ Cpack,
                                                  float* __restrict__ cn) {
    int r = blockIdx.x;
    int l = threadIdx.x;          // 0..63
    const float4* E4 = (const float4*)(E + (size_t)r * D_DIM);
    const float4* WA = (const float4*)(W + (size_t)l * D_DIM);
    const float4* WB = (const float4*)(W + (size_t)(l + 64) * D_DIM);

    float4 aA = make_float4(0.f, 0.f, 0.f, 0.f);
    float4 aB = make_float4(0.f, 0.f, 0.f, 0.f);
#pragma unroll
    for (int dd = 0; dd < 32; ++dd) {
        float4 e = E4[dd];
        float4 wa = WA[dd], wb = WB[dd];
        aA.x = fmaf(e.x, wa.x, aA.x);
        aA.y = fmaf(e.y, wa.y, aA.y);
        aA.z = fmaf(e.z, wa.z, aA.z);
        aA.w = fmaf(e.w, wa.w, aA.w);
        aB.x = fmaf(e.x, wb.x, aB.x);
        aB.y = fmaf(e.y, wb.y, aB.y);
        aB.z = fmaf(e.z, wb.z, aB.z);
        aB.w = fmaf(e.w, wb.w, aB.w);
    }
    float vA = ((aA.x + aA.y) + (aA.z + aA.w)) + b[l];
    float vB = ((aB.x + aB.y) + (aB.z + aB.w)) + b[l + 64];

    char* cp = Cpack + (size_t)(r >> 6) * 32768;
    int mt = (r >> 5) & 1, rs = r & 31;
    {   // d = l
        int kc = l >> 4, hf = (l >> 3) & 1, j = l & 7;
        float f = vA * SCALE;
        _Float16 h = (_Float16)f;
        _Float16 m = (_Float16)(f - (float)h);
        size_t off = (size_t)((mt * 8 + kc) * 1024 + (hf * 32 + rs) * 16 + j * 2);
        *(_Float16*)(cp + off) = h;
        *(_Float16*)(cp + off + 16384) = m;
    }
    {   // d = l + 64
        int d = l + 64;
        int kc = d >> 4, hf = (d >> 3) & 1, j = d & 7;
        float f = vB * SCALE;
        _Float16 h = (_Float16)f;
        _Float16 m = (_Float16)(f - (float)h);
        size_t off = (size_t)((mt * 8 + kc) * 1024 + (hf * 32 + rs) * 16 + j * 2);
        *(_Float16*)(cp + off) = h;
        *(_Float16*)(cp + off + 16384) = m;
    }

    float s = vA * vA + vB * vB;
#pragma unroll
    for (int off = 32; off > 0; off >>= 1) s += __shfl_down(s, off, 64);
    if (l == 0) cn[r] = s;
}

// ---------------- znorm (bit-identical) + fused inits ----------------
__global__ __launch_bounds__(64) void znorm_kernel(const float* __restrict__ Z,
                                                   float* __restrict__ zn,
                                                   ull* __restrict__ packed,
                                                   int* __restrict__ counts,
                                                   float* __restrict__ loss) {
    int t = blockIdx.x;
    int l = threadIdx.x;
    float a = Z[(size_t)t * D_DIM + l];
    float b2 = Z[(size_t)t * D_DIM + 64 + l];
    float s = a * a + b2 * b2;
#pragma unroll
    for (int off = 32; off > 0; off >>= 1) s += __shfl_down(s, off, 64);
    if (l == 0) {
        zn[t] = s;
        packed[t] = ~0ull;
        if (t < K_CODE) counts[t] = 0;
        if (t == 0) loss[0] = 0.f;
    }
}

// ---------------- prep_z: z -> f16 split packs (B-fragment layout) ----------
__global__ __launch_bounds__(256) void prep_z_kernel(const float* __restrict__ Z,
                                                     char* __restrict__ Zpack) {
    int tb = blockIdx.x;          // 32-token group
    int tid = threadIdx.x;
    int lane = tid & 63;
    int w = tid >> 6;
    char* zp = Zpack + (size_t)tb * 16384;
#pragma unroll
    for (int kq = 0; kq < 2; ++kq) {
        int kc = 2 * w + kq;
        const float* src = Z + (size_t)(tb * 32 + (lane & 31)) * D_DIM
                             + kc * 16 + (lane >> 5) * 8;
        float4 a = *(const float4*)(src);
        float4 c = *(const float4*)(src + 4);
        float vals[8] = {a.x, a.y, a.z, a.w, c.x, c.y, c.z, c.w};
        v8h h, m;
#pragma unroll
        for (int j = 0; j < 8; ++j) {
            float f = vals[j] * SCALE;
            _Float16 hh = (_Float16)f;
            h[j] = hh;
            m[j] = (_Float16)(f - (float)hh);
        }
        *(v8h*)(zp + (size_t)(kc * 1024 + lane * 16)) = h;
        *(v8h*)(zp + (size_t)(8192 + kc * 1024 + lane * 16)) = m;
    }
}

// ---------------- MFMA argmin ----------------
// D = A(codes) x B(tokens). 4 f16 MFMA passes per k-chunk realize fp32-class
// dot products (22-bit inputs, fp32 accum). Code tile (64 codes, full depth,
// both splits = 32 KB) staged in LDS once; token frags streamed coalesced from
// global Zpack; barrier-free K-loop. Per lane: 16 regs = 16 codes for ONE
// token -> in-lane argmin, one cross-half combine, packed-u64 atomicMin.
__global__ __launch_bounds__(256, 4) void argmin_kernel(const char* __restrict__ Zpack,
                                                        const char* __restrict__ Cpack,
                                                        const float* __restrict__ cn,
                                                        const float* __restrict__ zn,
                                                        ull* __restrict__ packed) {
    __shared__ char lds[33024];   // 32768 A-pack + 256 cn

    int tid = threadIdx.x;
    int lane = tid & 63;
    int w = __builtin_amdgcn_readfirstlane(tid >> 6);
    int cb = blockIdx.x;          // code block (64 codes)
    int nb = cb * BN;
    int mb = blockIdx.y * BM;     // token block (256 tokens)

    // ---- stage code pack (contiguous 32 KB) + cn slice ----
    {
        const float4* src = (const float4*)(Cpack + (size_t)cb * 32768);
        float4* dst = (float4*)lds;
#pragma unroll
        for (int it = 0; it < 8; ++it) dst[it * 256 + tid] = src[it * 256 + tid];
        if (tid < 64) *(float*)(lds + 32768 + tid * 4) = cn[nb + tid];
    }
    __syncthreads();

    v16f acc[2][2];               // [mt codes][nt tokens]
#pragma unroll
    for (int mt = 0; mt < 2; ++mt)
#pragma unroll
        for (int nt = 0; nt < 2; ++nt) acc[mt][nt] = (v16f)0.f;

    // token fragment base pointers: wave w owns tokens [mb+64w, mb+64w+64)
    int tb0 = (mb >> 5) + 2 * w;
    const char* zb00 = Zpack + (size_t)tb0 * 16384 + lane * 16;          // nt0,h
    const char* zb01 = zb00 + 8192;                                      // nt0,m
    const char* zb10 = Zpack + (size_t)(tb0 + 1) * 16384 + lane * 16;    // nt1,h
    const char* zb11 = zb10 + 8192;                                      // nt1,m
    const char* ab = lds + lane * 16;

#pragma unroll
    for (int kc = 0; kc < 8; ++kc) {
        v8h Ah0 = *(const v8h*)(ab + (0 * 8 + kc) * 1024);       // mt0 hi
        v8h Ah1 = *(const v8h*)(ab + (1 * 8 + kc) * 1024);       // mt1 hi
        v8h Am0 = *(const v8h*)(ab + (2 * 8 + kc) * 1024);       // mt0 lo
        v8h Am1 = *(const v8h*)(ab + (3 * 8 + kc) * 1024);       // mt1 lo
        v8h Bh0 = *(const v8h*)(zb00 + kc * 1024);
        v8h Bm0 = *(const v8h*)(zb01 + kc * 1024);
        v8h Bh1 = *(const v8h*)(zb10 + kc * 1024);
        v8h Bm1 = *(const v8h*)(zb11 + kc * 1024);

        acc[0][0] = __builtin_amdgcn_mfma_f32_32x32x16_f16(Ah0, Bh0, acc[0][0], 0, 0, 0);
        acc[0][1] = __builtin_amdgcn_mfma_f32_32x32x16_f16(Ah0, Bh1, acc[0][1], 0, 0, 0);
        acc[1][0] = __builtin_amdgcn_mfma_f32_32x32x16_f16(Ah1, Bh0, acc[1][0], 0, 0, 0);
        acc[1][1] = __builtin_amdgcn_mfma_f32_32x32x16_f16(Ah1, Bh1, acc[1][1], 0, 0, 0);
        acc[0][0] = __builtin_amdgcn_mfma_f32_32x32x16_f16(Ah0, Bm0, acc[0][0], 0, 0, 0);
        acc[0][1] = __builtin_amdgcn_mfma_f32_32x32x16_f16(Ah0, Bm1, acc[0][1], 0, 0, 0);
        acc[1][0] = __builtin_amdgcn_mfma_f32_32x32x16_f16(Ah1, Bm0, acc[1][0], 0, 0, 0);
        acc[1][1] = __builtin_amdgcn_mfma_f32_32x32x16_f16(Ah1, Bm1, acc[1][1], 0, 0, 0);
        acc[0][0] = __builtin_amdgcn_mfma_f32_32x32x16_f16(Am0, Bh0, acc[0][0], 0, 0, 0);
        acc[0][1] = __builtin_amdgcn_mfma_f32_32x32x16_f16(Am0, Bh1, acc[0][1], 0, 0, 0);
        acc[1][0] = __builtin_amdgcn_mfma_f32_32x32x16_f16(Am1, Bh0, acc[1][0], 0, 0, 0);
        acc[1][1] = __builtin_amdgcn_mfma_f32_32x32x16_f16(Am1, Bh1, acc[1][1], 0, 0, 0);
        acc[0][0] = __builtin_amdgcn_mfma_f32_32x32x16_f16(Am0, Bm0, acc[0][0], 0, 0, 0);
        acc[0][1] = __builtin_amdgcn_mfma_f32_32x32x16_f16(Am0, Bm1, acc[0][1], 0, 0, 0);
        acc[1][0] = __builtin_amdgcn_mfma_f32_32x32x16_f16(Am1, Bm0, acc[1][0], 0, 0, 0);
        acc[1][1] = __builtin_amdgcn_mfma_f32_32x32x16_f16(Am1, Bm1, acc[1][1], 0, 0, 0);
    }

    // ---- epilogue: in-lane argmin over this block's 64 codes ----
    const float* cn_s = (const float*)(lds + 32768);
    int half_id = lane >> 5;
    int tok0 = mb + w * 64 + (lane & 31);   // nt=0
    int tok1 = tok0 + 32;                   // nt=1
    float zn0 = zn[tok0], zn1 = zn[tok1];

    float best0 = 3.4e38f, best1 = 3.4e38f;
    int bi0 = nb, bi1 = nb;
#pragma unroll
    for (int mt = 0; mt < 2; ++mt) {
#pragma unroll
        for (int reg = 0; reg < 16; ++reg) {
            // ascending code order within half -> strict < keeps first-min
            int mrow = 32 * mt + (reg & 3) + 8 * (reg >> 2) + 4 * half_id;
            float cnv = cn_s[mrow];
            int code = nb + mrow;
            // s = (zn + cn) - 2*dot ; dot = acc*2^-24 (exact scale), fused:
            float s0 = fmaf(acc[mt][0][reg], ACC_SCALE, zn0 + cnv);
            float s1 = fmaf(acc[mt][1][reg], ACC_SCALE, zn1 + cnv);
            if (s0 < best0) { best0 = s0; bi0 = code; }
            if (s1 < best1) { best1 = s1; bi1 = code; }
        }
    }
    // cross-half combine with explicit smaller-idx tie-break
    {
        float ob = __shfl_xor(best0, 32, 64);
        int oi = __shfl_xor(bi0, 32, 64);
        if (ob < best0 || (ob == best0 && oi < bi0)) { best0 = ob; bi0 = oi; }
        ob = __shfl_xor(best1, 32, 64);
        oi = __shfl_xor(bi1, 32, 64);
        if (ob < best1 || (ob == best1 && oi < bi1)) { best1 = ob; bi1 = oi; }
    }
    // d > 0 -> f32 bits monotone as uint; idx in low bits -> first-min ties
    if (half_id == 0) {
        ull pk = ((ull)__float_as_uint(best0) << 32) | (unsigned)bi0;
        atomicMin(&packed[tok0], pk);
    } else {
        ull pk = ((ull)__float_as_uint(best1) << 32) | (unsigned)bi1;
        atomicMin(&packed[tok1], pk);
    }
}

// ---------------- zq: unpack winner, reconstruct code row, out + counts + loss
__global__ __launch_bounds__(256) void zq_kernel(const float* __restrict__ Z,
                                                 const char* __restrict__ Cpack,
                                                 const ull* __restrict__ packed,
                                                 float* __restrict__ out,
                                                 int* __restrict__ counts,
                                                 float* __restrict__ loss) {
    int gid = blockIdx.x * 256 + threadIdx.x;   // over T*D/4 float4s
    int t = gid >> 5;                           // 32 float4 per token
    int d4 = gid & 31;
    int idx = (int)(packed[t] & 0xFFFFFFFFull);
    if (d4 == 0) atomicAdd(&counts[idx], 1);

    // reconstruct c[d0..d0+3] = (ch + cm) * 2^-12 (exact sum: spans < 24 bits)
    int d0 = 4 * d4;
    int kc = d0 >> 4, hf = (d0 >> 3) & 1, j0 = d0 & 7;
    const char* cp = Cpack + (size_t)(idx >> 6) * 32768
                   + (size_t)((((idx >> 5) & 1) * 8 + kc) * 1024
                              + (hf * 32 + (idx & 31)) * 16 + j0 * 2);
    v4h h = *(const v4h*)(cp);
    v4h m = *(const v4h*)(cp + 16384);
    float4 cv;
    cv.x = ((float)h[0] + (float)m[0]) * DESCALE;
    cv.y = ((float)h[1] + (float)m[1]) * DESCALE;
    cv.z = ((float)h[2] + (float)m[2]) * DESCALE;
    cv.w = ((float)h[3] + (float)m[3]) * DESCALE;

    float4 zv = ((const float4*)Z)[gid];
    float dx = cv.x - zv.x, dy = cv.y - zv.y, dz = cv.z - zv.z, dw = cv.w - zv.w;
    float4 o;
    o.x = zv.x + dx;    // z + (z_q - z): match reference elementwise rounding
    o.y = zv.y + dy;
    o.z = zv.z + dz;
    o.w = zv.w + dw;
    ((float4*)out)[gid] = o;

    float ls = dx * dx + dy * dy + dz * dz + dw * dw;
#pragma unroll
    for (int off = 32; off > 0; off >>= 1) ls += __shfl_down(ls, off, 64);
    __shared__ float red[4];
    int lane = threadIdx.x & 63, w = threadIdx.x >> 6;
    if (lane == 0) red[w] = ls;
    __syncthreads();
    if (threadIdx.x == 0) {
        atomicAdd(loss, (red[0] + red[1]) + (red[2] + red[3]));
    }
}

// ---------------- scalars: commit_loss, perplexity ----------------
__global__ __launch_bounds__(256) void scalars_kernel(const int* __restrict__ counts,
                                                      const float* __restrict__ loss,
                                                      float* __restrict__ out) {
    float s = 0.f;
    for (int i = threadIdx.x; i < K_CODE; i += 256) {
        float e = (float)counts[i] * (1.0f / (float)T_TOK);
        s += e * logf(e + 1e-8f);
    }
#pragma unroll
    for (int off = 32; off > 0; off >>= 1) s += __shfl_down(s, off, 64);
    __shared__ float red[4];
    int lane = threadIdx.x & 63, w = threadIdx.x >> 6;
    if (lane == 0) red[w] = s;
    __syncthreads();
    if (threadIdx.x == 0) {
        float ssum = (red[0] + red[1]) + (red[2] + red[3]);
        out[(size_t)T_TOK * D_DIM + 0] = 1.25f * loss[0] / (float)((size_t)T_TOK * D_DIM);
        out[(size_t)T_TOK * D_DIM + 1] = expf(-ssum);
    }
}

extern "C" void kernel_launch(void* const* d_in, const int* in_sizes, int n_in,
                              void* d_out, int out_size, void* d_ws, size_t ws_size,
                              hipStream_t stream) {
    const float* z   = (const float*)d_in[0];   // [8,4096,128]
    const float* emb = (const float*)d_in[1];   // [8192,128]
    const float* pw  = (const float*)d_in[2];   // [128,128]
    const float* pb  = (const float*)d_in[3];   // [128]
    float* out = (float*)d_out;

    // Zpack (f16 split fragments, 16.78 MB) lives in d_out: dead scratch until
    // zq_kernel overwrites d_out with the final z_q_st.
    char* Zpack = (char*)d_out;

    char* ws = (char*)d_ws;
    // layout (bytes):
    //   Cpack:  0        .. 4194304   (128 cb x 32768)
    //   cn:     4194304  .. 4227072   (8192 f32)
    //   zn:     4227072  .. 4358144   (32768 f32)
    //   packed: 4358144  .. 4620288   (32768 u64)
    //   counts: 4620288  .. 4653056   (8192 i32)
    //   loss:   4653056  .. 4653060   (1 f32)
    char*  Cpack  = ws + 0;
    float* cn     = (float*)(ws + 4194304);
    float* zn     = (float*)(ws + 4227072);
    ull*   packed = (ull*)  (ws + 4358144);
    int*   counts = (int*)  (ws + 4620288);
    float* loss   = (float*)(ws + 4653056);

    proj_kernel<<<K_CODE, 64, 0, stream>>>(emb, pw, pb, Cpack, cn);
    prep_z_kernel<<<T_TOK / 32, 256, 0, stream>>>(z, Zpack);
    znorm_kernel<<<T_TOK, 64, 0, stream>>>(z, zn, packed, counts, loss);
    argmin_kernel<<<dim3(K_CODE / BN, T_TOK / BM), 256, 0, stream>>>(Zpack, Cpack, cn, zn, packed);
    zq_kernel<<<(T_TOK * D_DIM / 4) / 256, 256, 0, stream>>>(z, Cpack, packed, out, counts, loss);
    scalars_kernel<<<1, 256, 0, stream>>>(counts, loss, out);
}

// Round 9
// 419.931 us; speedup vs baseline: 2.4516x; 1.1244x over previous
//
#include <hip/hip_runtime.h>
#include <math.h>

#define T_TOK 32768
#define D_DIM 128
#define K_CODE 8192
#define BM 256              // tokens per block (argmin)
#define BN 64               // codes per block (argmin)

typedef unsigned long long ull;
typedef _Float16 v8h __attribute__((ext_vector_type(8)));
typedef _Float16 v4h __attribute__((ext_vector_type(4)));
typedef float v16f __attribute__((ext_vector_type(16)));

#define SCALE 4096.0f        // 2^12: pushes f16 split residuals into normal range
#define DESCALE (1.0f / 4096.0f)
#define ACC_SCALE (-0x1p-23f)   // s = (zn+cn) - 2*dot, dot = acc*2^-24

// Cpack layout (bytes): [cb=code/64][ (s*2+mt)*8+kc ][lane64][j8 f16]
// Zpack layout (bytes): [tb=token/32][ s ][ kc ][lane64][j8 f16]

// ---------------- proj: codebook row -> f16 split packs + cn ----------------
__global__ __launch_bounds__(64) void proj_kernel(const float* __restrict__ E,
                                                  const float* __restrict__ W,
                                                  const float* __restrict__ b,
                                                  char* __restrict__ Cpack,
                                                  float* __restrict__ cn) {
    int r = blockIdx.x;
    int l = threadIdx.x;          // 0..63
    const float4* E4 = (const float4*)(E + (size_t)r * D_DIM);
    const float4* WA = (const float4*)(W + (size_t)l * D_DIM);
    const float4* WB = (const float4*)(W + (size_t)(l + 64) * D_DIM);

    float4 aA = make_float4(0.f, 0.f, 0.f, 0.f);
    float4 aB = make_float4(0.f, 0.f, 0.f, 0.f);
#pragma unroll
    for (int dd = 0; dd < 32; ++dd) {
        float4 e = E4[dd];
        float4 wa = WA[dd], wb = WB[dd];
        aA.x = fmaf(e.x, wa.x, aA.x);
        aA.y = fmaf(e.y, wa.y, aA.y);
        aA.z = fmaf(e.z, wa.z, aA.z);
        aA.w = fmaf(e.w, wa.w, aA.w);
        aB.x = fmaf(e.x, wb.x, aB.x);
        aB.y = fmaf(e.y, wb.y, aB.y);
        aB.z = fmaf(e.z, wb.z, aB.z);
        aB.w = fmaf(e.w, wb.w, aB.w);
    }
    float vA = ((aA.x + aA.y) + (aA.z + aA.w)) + b[l];
    float vB = ((aB.x + aB.y) + (aB.z + aB.w)) + b[l + 64];

    char* cp = Cpack + (size_t)(r >> 6) * 32768;
    int mt = (r >> 5) & 1, rs = r & 31;
    {   // d = l
        int kc = l >> 4, hf = (l >> 3) & 1, j = l & 7;
        float f = vA * SCALE;
        _Float16 h = (_Float16)f;
        _Float16 m = (_Float16)(f - (float)h);
        size_t off = (size_t)((mt * 8 + kc) * 1024 + (hf * 32 + rs) * 16 + j * 2);
        *(_Float16*)(cp + off) = h;
        *(_Float16*)(cp + off + 16384) = m;
    }
    {   // d = l + 64
        int d = l + 64;
        int kc = d >> 4, hf = (d >> 3) & 1, j = d & 7;
        float f = vB * SCALE;
        _Float16 h = (_Float16)f;
        _Float16 m = (_Float16)(f - (float)h);
        size_t off = (size_t)((mt * 8 + kc) * 1024 + (hf * 32 + rs) * 16 + j * 2);
        *(_Float16*)(cp + off) = h;
        *(_Float16*)(cp + off + 16384) = m;
    }

    float s = vA * vA + vB * vB;
#pragma unroll
    for (int off = 32; off > 0; off >>= 1) s += __shfl_down(s, off, 64);
    if (l == 0) cn[r] = s;
}

// ---------------- znorm (bit-identical) + fused inits ----------------
__global__ __launch_bounds__(64) void znorm_kernel(const float* __restrict__ Z,
                                                   float* __restrict__ zn,
                                                   ull* __restrict__ packed,
                                                   int* __restrict__ counts,
                                                   float* __restrict__ loss) {
    int t = blockIdx.x;
    int l = threadIdx.x;
    float a = Z[(size_t)t * D_DIM + l];
    float b2 = Z[(size_t)t * D_DIM + 64 + l];
    float s = a * a + b2 * b2;
#pragma unroll
    for (int off = 32; off > 0; off >>= 1) s += __shfl_down(s, off, 64);
    if (l == 0) {
        zn[t] = s;
        packed[t] = ~0ull;
        if (t < K_CODE) counts[t] = 0;
        if (t == 0) loss[0] = 0.f;
    }
}

// ---------------- prep_z: z -> f16 split packs (B-fragment layout) ----------
__global__ __launch_bounds__(256) void prep_z_kernel(const float* __restrict__ Z,
                                                     char* __restrict__ Zpack) {
    int tb = blockIdx.x;          // 32-token group
    int tid = threadIdx.x;
    int lane = tid & 63;
    int w = tid >> 6;
    char* zp = Zpack + (size_t)tb * 16384;
#pragma unroll
    for (int kq = 0; kq < 2; ++kq) {
        int kc = 2 * w + kq;
        const float* src = Z + (size_t)(tb * 32 + (lane & 31)) * D_DIM
                             + kc * 16 + (lane >> 5) * 8;
        float4 a = *(const float4*)(src);
        float4 c = *(const float4*)(src + 4);
        float vals[8] = {a.x, a.y, a.z, a.w, c.x, c.y, c.z, c.w};
        v8h h, m;
#pragma unroll
        for (int j = 0; j < 8; ++j) {
            float f = vals[j] * SCALE;
            _Float16 hh = (_Float16)f;
            h[j] = hh;
            m[j] = (_Float16)(f - (float)hh);
        }
        *(v8h*)(zp + (size_t)(kc * 1024 + lane * 16)) = h;
        *(v8h*)(zp + (size_t)(8192 + kc * 1024 + lane * 16)) = m;
    }
}

// ---------------- MFMA argmin (3-pass + register-prefetched B) ----------------
// R8 lesson: MfmaUtil 50% with VGPR_Count=60 -> compiler had no headroom to
// prefetch the per-kc global B-frags, exposing L2 latency every kc. Now:
// (1) m*m MFMA pass dropped (error <= 2^-24|z||c| summed ~4e-7 on s, below the
//     fp32 accum noise already present) -> 12 MFMA/kc, floor 115 -> 86 us;
// (2) explicit next-kc B double-buffer in regs + launch_bounds(256,3).
__global__ __launch_bounds__(256, 3) void argmin_kernel(const char* __restrict__ Zpack,
                                                        const char* __restrict__ Cpack,
                                                        const float* __restrict__ cn,
                                                        const float* __restrict__ zn,
                                                        ull* __restrict__ packed) {
    __shared__ char lds[33024];   // 32768 A-pack + 256 cn

    int tid = threadIdx.x;
    int lane = tid & 63;
    int w = __builtin_amdgcn_readfirstlane(tid >> 6);
    int cb = blockIdx.x;          // code block (64 codes)
    int nb = cb * BN;
    int mb = blockIdx.y * BM;     // token block (256 tokens)

    // ---- stage code pack (contiguous 32 KB) + cn slice ----
    {
        const float4* src = (const float4*)(Cpack + (size_t)cb * 32768);
        float4* dst = (float4*)lds;
#pragma unroll
        for (int it = 0; it < 8; ++it) dst[it * 256 + tid] = src[it * 256 + tid];
        if (tid < 64) *(float*)(lds + 32768 + tid * 4) = cn[nb + tid];
    }
    __syncthreads();

    v16f acc[2][2];               // [mt codes][nt tokens]
#pragma unroll
    for (int mt = 0; mt < 2; ++mt)
#pragma unroll
        for (int nt = 0; nt < 2; ++nt) acc[mt][nt] = (v16f)0.f;

    // token fragment base pointers: wave w owns tokens [mb+64w, mb+64w+64)
    int tb0 = (mb >> 5) + 2 * w;
    const char* zb00 = Zpack + (size_t)tb0 * 16384 + lane * 16;          // nt0,h
    const char* zb01 = zb00 + 8192;                                      // nt0,m
    const char* zb10 = Zpack + (size_t)(tb0 + 1) * 16384 + lane * 16;    // nt1,h
    const char* zb11 = zb10 + 8192;                                      // nt1,m
    const char* ab = lds + lane * 16;

    // prefetch kc=0 B-frags
    v8h pBh0 = *(const v8h*)(zb00);
    v8h pBm0 = *(const v8h*)(zb01);
    v8h pBh1 = *(const v8h*)(zb10);
    v8h pBm1 = *(const v8h*)(zb11);

#pragma unroll
    for (int kc = 0; kc < 8; ++kc) {
        v8h Bh0 = pBh0, Bm0 = pBm0, Bh1 = pBh1, Bm1 = pBm1;
        if (kc < 7) {   // issue next-kc loads before this kc's MFMAs
            pBh0 = *(const v8h*)(zb00 + (kc + 1) * 1024);
            pBm0 = *(const v8h*)(zb01 + (kc + 1) * 1024);
            pBh1 = *(const v8h*)(zb10 + (kc + 1) * 1024);
            pBm1 = *(const v8h*)(zb11 + (kc + 1) * 1024);
        }
        v8h Ah0 = *(const v8h*)(ab + (0 * 8 + kc) * 1024);       // mt0 hi
        v8h Ah1 = *(const v8h*)(ab + (1 * 8 + kc) * 1024);       // mt1 hi
        v8h Am0 = *(const v8h*)(ab + (2 * 8 + kc) * 1024);       // mt0 lo
        v8h Am1 = *(const v8h*)(ab + (3 * 8 + kc) * 1024);       // mt1 lo

        acc[0][0] = __builtin_amdgcn_mfma_f32_32x32x16_f16(Ah0, Bh0, acc[0][0], 0, 0, 0);
        acc[0][1] = __builtin_amdgcn_mfma_f32_32x32x16_f16(Ah0, Bh1, acc[0][1], 0, 0, 0);
        acc[1][0] = __builtin_amdgcn_mfma_f32_32x32x16_f16(Ah1, Bh0, acc[1][0], 0, 0, 0);
        acc[1][1] = __builtin_amdgcn_mfma_f32_32x32x16_f16(Ah1, Bh1, acc[1][1], 0, 0, 0);
        acc[0][0] = __builtin_amdgcn_mfma_f32_32x32x16_f16(Ah0, Bm0, acc[0][0], 0, 0, 0);
        acc[0][1] = __builtin_amdgcn_mfma_f32_32x32x16_f16(Ah0, Bm1, acc[0][1], 0, 0, 0);
        acc[1][0] = __builtin_amdgcn_mfma_f32_32x32x16_f16(Ah1, Bm0, acc[1][0], 0, 0, 0);
        acc[1][1] = __builtin_amdgcn_mfma_f32_32x32x16_f16(Ah1, Bm1, acc[1][1], 0, 0, 0);
        acc[0][0] = __builtin_amdgcn_mfma_f32_32x32x16_f16(Am0, Bh0, acc[0][0], 0, 0, 0);
        acc[0][1] = __builtin_amdgcn_mfma_f32_32x32x16_f16(Am0, Bh1, acc[0][1], 0, 0, 0);
        acc[1][0] = __builtin_amdgcn_mfma_f32_32x32x16_f16(Am1, Bh0, acc[1][0], 0, 0, 0);
        acc[1][1] = __builtin_amdgcn_mfma_f32_32x32x16_f16(Am1, Bh1, acc[1][1], 0, 0, 0);
    }

    // ---- epilogue: in-lane argmin over this block's 64 codes (as R8) ----
    const float* cn_s = (const float*)(lds + 32768);
    int half_id = lane >> 5;
    int tok0 = mb + w * 64 + (lane & 31);   // nt=0
    int tok1 = tok0 + 32;                   // nt=1
    float zn0 = zn[tok0], zn1 = zn[tok1];

    float best0 = 3.4e38f, best1 = 3.4e38f;
    int bi0 = nb, bi1 = nb;
#pragma unroll
    for (int mt = 0; mt < 2; ++mt) {
#pragma unroll
        for (int reg = 0; reg < 16; ++reg) {
            // ascending code order within half -> strict < keeps first-min
            int mrow = 32 * mt + (reg & 3) + 8 * (reg >> 2) + 4 * half_id;
            float cnv = cn_s[mrow];
            int code = nb + mrow;
            // s = (zn + cn) - 2*dot ; dot = acc*2^-24 (exact scale), fused:
            float s0 = fmaf(acc[mt][0][reg], ACC_SCALE, zn0 + cnv);
            float s1 = fmaf(acc[mt][1][reg], ACC_SCALE, zn1 + cnv);
            if (s0 < best0) { best0 = s0; bi0 = code; }
            if (s1 < best1) { best1 = s1; bi1 = code; }
        }
    }
    // cross-half combine with explicit smaller-idx tie-break
    {
        float ob = __shfl_xor(best0, 32, 64);
        int oi = __shfl_xor(bi0, 32, 64);
        if (ob < best0 || (ob == best0 && oi < bi0)) { best0 = ob; bi0 = oi; }
        ob = __shfl_xor(best1, 32, 64);
        oi = __shfl_xor(bi1, 32, 64);
        if (ob < best1 || (ob == best1 && oi < bi1)) { best1 = ob; bi1 = oi; }
    }
    // d > 0 -> f32 bits monotone as uint; idx in low bits -> first-min ties
    if (half_id == 0) {
        ull pk = ((ull)__float_as_uint(best0) << 32) | (unsigned)bi0;
        atomicMin(&packed[tok0], pk);
    } else {
        ull pk = ((ull)__float_as_uint(best1) << 32) | (unsigned)bi1;
        atomicMin(&packed[tok1], pk);
    }
}

// ---------------- zq: unpack winner, reconstruct code row, out + counts + loss
__global__ __launch_bounds__(256) void zq_kernel(const float* __restrict__ Z,
                                                 const char* __restrict__ Cpack,
                                                 const ull* __restrict__ packed,
                                                 float* __restrict__ out,
                                                 int* __restrict__ counts,
                                                 float* __restrict__ loss) {
    int gid = blockIdx.x * 256 + threadIdx.x;   // over T*D/4 float4s
    int t = gid >> 5;                           // 32 float4 per token
    int d4 = gid & 31;
    int idx = (int)(packed[t] & 0xFFFFFFFFull);
    if (d4 == 0) atomicAdd(&counts[idx], 1);

    // reconstruct c[d0..d0+3] = (ch + cm) * 2^-12 (exact sum: spans < 24 bits)
    int d0 = 4 * d4;
    int kc = d0 >> 4, hf = (d0 >> 3) & 1, j0 = d0 & 7;
    const char* cp = Cpack + (size_t)(idx >> 6) * 32768
                   + (size_t)((((idx >> 5) & 1) * 8 + kc) * 1024
                              + (hf * 32 + (idx & 31)) * 16 + j0 * 2);
    v4h h = *(const v4h*)(cp);
    v4h m = *(const v4h*)(cp + 16384);
    float4 cv;
    cv.x = ((float)h[0] + (float)m[0]) * DESCALE;
    cv.y = ((float)h[1] + (float)m[1]) * DESCALE;
    cv.z = ((float)h[2] + (float)m[2]) * DESCALE;
    cv.w = ((float)h[3] + (float)m[3]) * DESCALE;

    float4 zv = ((const float4*)Z)[gid];
    float dx = cv.x - zv.x, dy = cv.y - zv.y, dz = cv.z - zv.z, dw = cv.w - zv.w;
    float4 o;
    o.x = zv.x + dx;    // z + (z_q - z): match reference elementwise rounding
    o.y = zv.y + dy;
    o.z = zv.z + dz;
    o.w = zv.w + dw;
    ((float4*)out)[gid] = o;

    float ls = dx * dx + dy * dy + dz * dz + dw * dw;
#pragma unroll
    for (int off = 32; off > 0; off >>= 1) ls += __shfl_down(ls, off, 64);
    __shared__ float red[4];
    int lane = threadIdx.x & 63, w = threadIdx.x >> 6;
    if (lane == 0) red[w] = ls;
    __syncthreads();
    if (threadIdx.x == 0) {
        atomicAdd(loss, (red[0] + red[1]) + (red[2] + red[3]));
    }
}

// ---------------- scalars: commit_loss, perplexity ----------------
__global__ __launch_bounds__(256) void scalars_kernel(const int* __restrict__ counts,
                                                      const float* __restrict__ loss,
                                                      float* __restrict__ out) {
    float s = 0.f;
    for (int i = threadIdx.x; i < K_CODE; i += 256) {
        float e = (float)counts[i] * (1.0f / (float)T_TOK);
        s += e * logf(e + 1e-8f);
    }
#pragma unroll
    for (int off = 32; off > 0; off >>= 1) s += __shfl_down(s, off, 64);
    __shared__ float red[4];
    int lane = threadIdx.x & 63, w = threadIdx.x >> 6;
    if (lane == 0) red[w] = s;
    __syncthreads();
    if (threadIdx.x == 0) {
        float ssum = (red[0] + red[1]) + (red[2] + red[3]);
        out[(size_t)T_TOK * D_DIM + 0] = 1.25f * loss[0] / (float)((size_t)T_TOK * D_DIM);
        out[(size_t)T_TOK * D_DIM + 1] = expf(-ssum);
    }
}

extern "C" void kernel_launch(void* const* d_in, const int* in_sizes, int n_in,
                              void* d_out, int out_size, void* d_ws, size_t ws_size,
                              hipStream_t stream) {
    const float* z   = (const float*)d_in[0];   // [8,4096,128]
    const float* emb = (const float*)d_in[1];   // [8192,128]
    const float* pw  = (const float*)d_in[2];   // [128,128]
    const float* pb  = (const float*)d_in[3];   // [128]
    float* out = (float*)d_out;

    // Zpack (f16 split fragments, 16.78 MB) lives in d_out: dead scratch until
    // zq_kernel overwrites d_out with the final z_q_st.
    char* Zpack = (char*)d_out;

    char* ws = (char*)d_ws;
    // layout (bytes):
    //   Cpack:  0        .. 4194304   (128 cb x 32768)
    //   cn:     4194304  .. 4227072   (8192 f32)
    //   zn:     4227072  .. 4358144   (32768 f32)
    //   packed: 4358144  .. 4620288   (32768 u64)
    //   counts: 4620288  .. 4653056   (8192 i32)
    //   loss:   4653056  .. 4653060   (1 f32)
    char*  Cpack  = ws + 0;
    float* cn     = (float*)(ws + 4194304);
    float* zn     = (float*)(ws + 4227072);
    ull*   packed = (ull*)  (ws + 4358144);
    int*   counts = (int*)  (ws + 4620288);
    float* loss   = (float*)(ws + 4653056);

    proj_kernel<<<K_CODE, 64, 0, stream>>>(emb, pw, pb, Cpack, cn);
    prep_z_kernel<<<T_TOK / 32, 256, 0, stream>>>(z, Zpack);
    znorm_kernel<<<T_TOK, 64, 0, stream>>>(z, zn, packed, counts, loss);
    argmin_kernel<<<dim3(K_CODE / BN, T_TOK / BM), 256, 0, stream>>>(Zpack, Cpack, cn, zn, packed);
    zq_kernel<<<(T_TOK * D_DIM / 4) / 256, 256, 0, stream>>>(z, Cpack, packed, out, counts, loss);
    scalars_kernel<<<1, 256, 0, stream>>>(counts, loss, out);
}

// Round 10
// 408.710 us; speedup vs baseline: 2.5189x; 1.0275x over previous
//
#include <hip/hip_runtime.h>
#include <math.h>

#define T_TOK 32768
#define D_DIM 128
#define K_CODE 8192
#define BM 512              // tokens per block (argmin): 4 waves x 128
#define BN 64               // codes per block (argmin)

typedef unsigned long long ull;
typedef _Float16 v8h __attribute__((ext_vector_type(8)));
typedef _Float16 v4h __attribute__((ext_vector_type(4)));
typedef float v16f __attribute__((ext_vector_type(16)));

#define SCALE 4096.0f        // 2^12: pushes f16 split residuals into normal range
#define DESCALE (1.0f / 4096.0f)
#define ACC_SCALE (-0x1p-23f)   // s = (zn+cn) - 2*dot, dot = acc*2^-24

// Cpack layout (bytes): [cb=code/64][ (s*2+mt)*8+kc ][lane64][j8 f16]
// Zpack layout (bytes): [tb=token/32][ s ][ kc ][lane64][j8 f16]

// ---------------- proj: codebook row -> f16 split packs + cn ----------------
__global__ __launch_bounds__(64) void proj_kernel(const float* __restrict__ E,
                                                  const float* __restrict__ W,
                                                  const float* __restrict__ b,
                                                  char* __restrict__ Cpack,
                                                  float* __restrict__ cn) {
    int r = blockIdx.x;
    int l = threadIdx.x;          // 0..63
    const float4* E4 = (const float4*)(E + (size_t)r * D_DIM);
    const float4* WA = (const float4*)(W + (size_t)l * D_DIM);
    const float4* WB = (const float4*)(W + (size_t)(l + 64) * D_DIM);

    float4 aA = make_float4(0.f, 0.f, 0.f, 0.f);
    float4 aB = make_float4(0.f, 0.f, 0.f, 0.f);
#pragma unroll
    for (int dd = 0; dd < 32; ++dd) {
        float4 e = E4[dd];
        float4 wa = WA[dd], wb = WB[dd];
        aA.x = fmaf(e.x, wa.x, aA.x);
        aA.y = fmaf(e.y, wa.y, aA.y);
        aA.z = fmaf(e.z, wa.z, aA.z);
        aA.w = fmaf(e.w, wa.w, aA.w);
        aB.x = fmaf(e.x, wb.x, aB.x);
        aB.y = fmaf(e.y, wb.y, aB.y);
        aB.z = fmaf(e.z, wb.z, aB.z);
        aB.w = fmaf(e.w, wb.w, aB.w);
    }
    float vA = ((aA.x + aA.y) + (aA.z + aA.w)) + b[l];
    float vB = ((aB.x + aB.y) + (aB.z + aB.w)) + b[l + 64];

    char* cp = Cpack + (size_t)(r >> 6) * 32768;
    int mt = (r >> 5) & 1, rs = r & 31;
    {   // d = l
        int kc = l >> 4, hf = (l >> 3) & 1, j = l & 7;
        float f = vA * SCALE;
        _Float16 h = (_Float16)f;
        _Float16 m = (_Float16)(f - (float)h);
        size_t off = (size_t)((mt * 8 + kc) * 1024 + (hf * 32 + rs) * 16 + j * 2);
        *(_Float16*)(cp + off) = h;
        *(_Float16*)(cp + off + 16384) = m;
    }
    {   // d = l + 64
        int d = l + 64;
        int kc = d >> 4, hf = (d >> 3) & 1, j = d & 7;
        float f = vB * SCALE;
        _Float16 h = (_Float16)f;
        _Float16 m = (_Float16)(f - (float)h);
        size_t off = (size_t)((mt * 8 + kc) * 1024 + (hf * 32 + rs) * 16 + j * 2);
        *(_Float16*)(cp + off) = h;
        *(_Float16*)(cp + off + 16384) = m;
    }

    float s = vA * vA + vB * vB;
#pragma unroll
    for (int off = 32; off > 0; off >>= 1) s += __shfl_down(s, off, 64);
    if (l == 0) cn[r] = s;
}

// ---------------- znorm (bit-identical) + fused inits ----------------
__global__ __launch_bounds__(64) void znorm_kernel(const float* __restrict__ Z,
                                                   float* __restrict__ zn,
                                                   ull* __restrict__ packed,
                                                   int* __restrict__ counts,
                                                   float* __restrict__ loss) {
    int t = blockIdx.x;
    int l = threadIdx.x;
    float a = Z[(size_t)t * D_DIM + l];
    float b2 = Z[(size_t)t * D_DIM + 64 + l];
    float s = a * a + b2 * b2;
#pragma unroll
    for (int off = 32; off > 0; off >>= 1) s += __shfl_down(s, off, 64);
    if (l == 0) {
        zn[t] = s;
        packed[t] = ~0ull;
        if (t < K_CODE) counts[t] = 0;
        if (t == 0) loss[0] = 0.f;
    }
}

// ---------------- prep_z: z -> f16 split packs (B-fragment layout) ----------
__global__ __launch_bounds__(256) void prep_z_kernel(const float* __restrict__ Z,
                                                     char* __restrict__ Zpack) {
    int tb = blockIdx.x;          // 32-token group
    int tid = threadIdx.x;
    int lane = tid & 63;
    int w = tid >> 6;
    char* zp = Zpack + (size_t)tb * 16384;
#pragma unroll
    for (int kq = 0; kq < 2; ++kq) {
        int kc = 2 * w + kq;
        const float* src = Z + (size_t)(tb * 32 + (lane & 31)) * D_DIM
                             + kc * 16 + (lane >> 5) * 8;
        float4 a = *(const float4*)(src);
        float4 c = *(const float4*)(src + 4);
        float vals[8] = {a.x, a.y, a.z, a.w, c.x, c.y, c.z, c.w};
        v8h h, m;
#pragma unroll
        for (int j = 0; j < 8; ++j) {
            float f = vals[j] * SCALE;
            _Float16 hh = (_Float16)f;
            h[j] = hh;
            m[j] = (_Float16)(f - (float)hh);
        }
        *(v8h*)(zp + (size_t)(kc * 1024 + lane * 16)) = h;
        *(v8h*)(zp + (size_t)(8192 + kc * 1024 + lane * 16)) = m;
    }
}

// ---------------- MFMA argmin (nt=4: LDS/MFMA pipe-balanced) ----------------
// R9 lesson: 4 ds_read_b128 (48 LDS-cyc, single LDS unit) per 12 MFMA
// (24 wall-cyc across 4 SIMDs) -> LDS pipe 2x oversubscribed -> MfmaUtil 50%.
// nt=4 reuses the same A-frags over 24 MFMA -> 1:1 balance. acc 128 AGPR +
// 2-deep B prefetch (64 VGPR) needs launch_bounds(256,2).
__global__ __launch_bounds__(256, 2) void argmin_kernel(const char* __restrict__ Zpack,
                                                        const char* __restrict__ Cpack,
                                                        const float* __restrict__ cn,
                                                        const float* __restrict__ zn,
                                                        ull* __restrict__ packed) {
    __shared__ char lds[33024];   // 32768 A-pack + 256 cn

    int tid = threadIdx.x;
    int lane = tid & 63;
    int w = __builtin_amdgcn_readfirstlane(tid >> 6);
    int cb = blockIdx.x;          // code block (64 codes)
    int nb = cb * BN;
    int mb = blockIdx.y * BM;     // token block (512 tokens)

    // ---- stage code pack (contiguous 32 KB) + cn slice ----
    {
        const float4* src = (const float4*)(Cpack + (size_t)cb * 32768);
        float4* dst = (float4*)lds;
#pragma unroll
        for (int it = 0; it < 8; ++it) dst[it * 256 + tid] = src[it * 256 + tid];
        if (tid < 64) *(float*)(lds + 32768 + tid * 4) = cn[nb + tid];
    }
    __syncthreads();

    v16f acc[2][4];               // [mt codes][n token-groups]
#pragma unroll
    for (int mt = 0; mt < 2; ++mt)
#pragma unroll
        for (int n = 0; n < 4; ++n) acc[mt][n] = (v16f)0.f;

    // wave w owns token groups tbw..tbw+3 (128 tokens)
    int tbw = (mb >> 5) + 4 * w;
    const char* zb0 = Zpack + (size_t)tbw * 16384 + lane * 16;
    const char* ab = lds + lane * 16;

    // 2-deep register prefetch: pb[frag = n*2 + split][buf = kc&1]
    v8h pb[8][2];
#pragma unroll
    for (int n = 0; n < 4; ++n) {
        pb[2 * n + 0][0] = *(const v8h*)(zb0 + n * 16384);
        pb[2 * n + 1][0] = *(const v8h*)(zb0 + n * 16384 + 8192);
        pb[2 * n + 0][1] = *(const v8h*)(zb0 + n * 16384 + 1024);
        pb[2 * n + 1][1] = *(const v8h*)(zb0 + n * 16384 + 8192 + 1024);
    }

#pragma unroll
    for (int kc = 0; kc < 8; ++kc) {
        int cur = kc & 1;
        v8h Bh[4], Bm[4];
#pragma unroll
        for (int n = 0; n < 4; ++n) { Bh[n] = pb[2 * n][cur]; Bm[n] = pb[2 * n + 1][cur]; }
        if (kc < 6) {   // refill this buffer with kc+2 before the MFMAs
#pragma unroll
            for (int n = 0; n < 4; ++n) {
                pb[2 * n + 0][cur] = *(const v8h*)(zb0 + n * 16384 + (kc + 2) * 1024);
                pb[2 * n + 1][cur] = *(const v8h*)(zb0 + n * 16384 + 8192 + (kc + 2) * 1024);
            }
        }
        v8h Ah0 = *(const v8h*)(ab + (0 * 8 + kc) * 1024);       // mt0 hi
        v8h Ah1 = *(const v8h*)(ab + (1 * 8 + kc) * 1024);       // mt1 hi
        v8h Am0 = *(const v8h*)(ab + (2 * 8 + kc) * 1024);       // mt0 lo
        v8h Am1 = *(const v8h*)(ab + (3 * 8 + kc) * 1024);       // mt1 lo

        // pass h*h (same-acc distance = 8)
#pragma unroll
        for (int n = 0; n < 4; ++n)
            acc[0][n] = __builtin_amdgcn_mfma_f32_32x32x16_f16(Ah0, Bh[n], acc[0][n], 0, 0, 0);
#pragma unroll
        for (int n = 0; n < 4; ++n)
            acc[1][n] = __builtin_amdgcn_mfma_f32_32x32x16_f16(Ah1, Bh[n], acc[1][n], 0, 0, 0);
        // pass h*m
#pragma unroll
        for (int n = 0; n < 4; ++n)
            acc[0][n] = __builtin_amdgcn_mfma_f32_32x32x16_f16(Ah0, Bm[n], acc[0][n], 0, 0, 0);
#pragma unroll
        for (int n = 0; n < 4; ++n)
            acc[1][n] = __builtin_amdgcn_mfma_f32_32x32x16_f16(Ah1, Bm[n], acc[1][n], 0, 0, 0);
        // pass m*h
#pragma unroll
        for (int n = 0; n < 4; ++n)
            acc[0][n] = __builtin_amdgcn_mfma_f32_32x32x16_f16(Am0, Bh[n], acc[0][n], 0, 0, 0);
#pragma unroll
        for (int n = 0; n < 4; ++n)
            acc[1][n] = __builtin_amdgcn_mfma_f32_32x32x16_f16(Am1, Bh[n], acc[1][n], 0, 0, 0);
    }

    // ---- epilogue: in-lane argmin per token group, cross-half combine ----
    const float* cn_s = (const float*)(lds + 32768);
    int half_id = lane >> 5;

#pragma unroll
    for (int n = 0; n < 4; ++n) {
        int tok = mb + w * 128 + n * 32 + (lane & 31);
        float znv = zn[tok];
        float best = 3.4e38f;
        int bi = nb;
#pragma unroll
        for (int mt = 0; mt < 2; ++mt) {
#pragma unroll
            for (int reg = 0; reg < 16; ++reg) {
                // ascending code order within half -> strict < keeps first-min
                int mrow = 32 * mt + (reg & 3) + 8 * (reg >> 2) + 4 * half_id;
                float cnv = cn_s[mrow];
                int code = nb + mrow;
                // s = (zn + cn) - 2*dot ; dot = acc*2^-24 (exact scale), fused:
                float s = fmaf(acc[mt][n][reg], ACC_SCALE, znv + cnv);
                if (s < best) { best = s; bi = code; }
            }
        }
        // cross-half combine with explicit smaller-idx tie-break
        float ob = __shfl_xor(best, 32, 64);
        int oi = __shfl_xor(bi, 32, 64);
        if (ob < best || (ob == best && oi < bi)) { best = ob; bi = oi; }
        // d > 0 -> f32 bits monotone as uint; idx in low bits -> first-min ties
        // split the 4 groups' atomics across the two halves (2 per lane)
        if ((n >> 1) == half_id) {
            ull pk = ((ull)__float_as_uint(best) << 32) | (unsigned)bi;
            atomicMin(&packed[tok], pk);
        }
    }
}

// ---------------- zq: unpack winner, reconstruct code row, out + counts + loss
__global__ __launch_bounds__(256) void zq_kernel(const float* __restrict__ Z,
                                                 const char* __restrict__ Cpack,
                                                 const ull* __restrict__ packed,
                                                 float* __restrict__ out,
                                                 int* __restrict__ counts,
                                                 float* __restrict__ loss) {
    int gid = blockIdx.x * 256 + threadIdx.x;   // over T*D/4 float4s
    int t = gid >> 5;                           // 32 float4 per token
    int d4 = gid & 31;
    int idx = (int)(packed[t] & 0xFFFFFFFFull);
    if (d4 == 0) atomicAdd(&counts[idx], 1);

    // reconstruct c[d0..d0+3] = (ch + cm) * 2^-12 (exact sum: spans < 24 bits)
    int d0 = 4 * d4;
    int kc = d0 >> 4, hf = (d0 >> 3) & 1, j0 = d0 & 7;
    const char* cp = Cpack + (size_t)(idx >> 6) * 32768
                   + (size_t)((((idx >> 5) & 1) * 8 + kc) * 1024
                              + (hf * 32 + (idx & 31)) * 16 + j0 * 2);
    v4h h = *(const v4h*)(cp);
    v4h m = *(const v4h*)(cp + 16384);
    float4 cv;
    cv.x = ((float)h[0] + (float)m[0]) * DESCALE;
    cv.y = ((float)h[1] + (float)m[1]) * DESCALE;
    cv.z = ((float)h[2] + (float)m[2]) * DESCALE;
    cv.w = ((float)h[3] + (float)m[3]) * DESCALE;

    float4 zv = ((const float4*)Z)[gid];
    float dx = cv.x - zv.x, dy = cv.y - zv.y, dz = cv.z - zv.z, dw = cv.w - zv.w;
    float4 o;
    o.x = zv.x + dx;    // z + (z_q - z): match reference elementwise rounding
    o.y = zv.y + dy;
    o.z = zv.z + dz;
    o.w = zv.w + dw;
    ((float4*)out)[gid] = o;

    float ls = dx * dx + dy * dy + dz * dz + dw * dw;
#pragma unroll
    for (int off = 32; off > 0; off >>= 1) ls += __shfl_down(ls, off, 64);
    __shared__ float red[4];
    int lane = threadIdx.x & 63, w = threadIdx.x >> 6;
    if (lane == 0) red[w] = ls;
    __syncthreads();
    if (threadIdx.x == 0) {
        atomicAdd(loss, (red[0] + red[1]) + (red[2] + red[3]));
    }
}

// ---------------- scalars: commit_loss, perplexity ----------------
__global__ __launch_bounds__(256) void scalars_kernel(const int* __restrict__ counts,
                                                      const float* __restrict__ loss,
                                                      float* __restrict__ out) {
    float s = 0.f;
    for (int i = threadIdx.x; i < K_CODE; i += 256) {
        float e = (float)counts[i] * (1.0f / (float)T_TOK);
        s += e * logf(e + 1e-8f);
    }
#pragma unroll
    for (int off = 32; off > 0; off >>= 1) s += __shfl_down(s, off, 64);
    __shared__ float red[4];
    int lane = threadIdx.x & 63, w = threadIdx.x >> 6;
    if (lane == 0) red[w] = s;
    __syncthreads();
    if (threadIdx.x == 0) {
        float ssum = (red[0] + red[1]) + (red[2] + red[3]);
        out[(size_t)T_TOK * D_DIM + 0] = 1.25f * loss[0] / (float)((size_t)T_TOK * D_DIM);
        out[(size_t)T_TOK * D_DIM + 1] = expf(-ssum);
    }
}

extern "C" void kernel_launch(void* const* d_in, const int* in_sizes, int n_in,
                              void* d_out, int out_size, void* d_ws, size_t ws_size,
                              hipStream_t stream) {
    const float* z   = (const float*)d_in[0];   // [8,4096,128]
    const float* emb = (const float*)d_in[1];   // [8192,128]
    const float* pw  = (const float*)d_in[2];   // [128,128]
    const float* pb  = (const float*)d_in[3];   // [128]
    float* out = (float*)d_out;

    // Zpack (f16 split fragments, 16.78 MB) lives in d_out: dead scratch until
    // zq_kernel overwrites d_out with the final z_q_st.
    char* Zpack = (char*)d_out;

    char* ws = (char*)d_ws;
    // layout (bytes):
    //   Cpack:  0        .. 4194304   (128 cb x 32768)
    //   cn:     4194304  .. 4227072   (8192 f32)
    //   zn:     4227072  .. 4358144   (32768 f32)
    //   packed: 4358144  .. 4620288   (32768 u64)
    //   counts: 4620288  .. 4653056   (8192 i32)
    //   loss:   4653056  .. 4653060   (1 f32)
    char*  Cpack  = ws + 0;
    float* cn     = (float*)(ws + 4194304);
    float* zn     = (float*)(ws + 4227072);
    ull*   packed = (ull*)  (ws + 4358144);
    int*   counts = (int*)  (ws + 4620288);
    float* loss   = (float*)(ws + 4653056);

    proj_kernel<<<K_CODE, 64, 0, stream>>>(emb, pw, pb, Cpack, cn);
    prep_z_kernel<<<T_TOK / 32, 256, 0, stream>>>(z, Zpack);
    znorm_kernel<<<T_TOK, 64, 0, stream>>>(z, zn, packed, counts, loss);
    argmin_kernel<<<dim3(K_CODE / BN, T_TOK / BM), 256, 0, stream>>>(Zpack, Cpack, cn, zn, packed);
    zq_kernel<<<(T_TOK * D_DIM / 4) / 256, 256, 0, stream>>>(z, Cpack, packed, out, counts, loss);
    scalars_kernel<<<1, 256, 0, stream>>>(counts, loss, out);
}